// Round 10
// baseline (1269.220 us; speedup 1.0000x reference)
//
#include <hip/hip_runtime.h>
#include <math.h>

#define NPTS 4096
#define BATCH 8
#define HIDD 512
#define ROWS 32768
#define R_ATT2 0.04f
#define INV_SQRT_D 0.08838834764831845f

typedef unsigned short u16;
typedef unsigned int u32;
typedef __attribute__((ext_vector_type(8))) short s8v;
typedef __attribute__((ext_vector_type(4))) float f4v;

__device__ __forceinline__ float u2f(u16 v) { return __uint_as_float(((u32)v) << 16); }
__device__ __forceinline__ u16 f2u(float f) {         // RNE fp32->bf16
  u32 u = __float_as_uint(f);
  return (u16)((u + 0x7fffu + ((u >> 16) & 1u)) >> 16);
}

// ---------------------------------------------------------------------------
// G = wq^T @ wk (3x3)
__global__ void gram_k(const float* __restrict__ wq, const float* __restrict__ wk,
                       float* __restrict__ G) {
  int ab = threadIdx.x;
  if (ab < 9) {
    int a = ab / 3, b = ab % 3;
    float s = 0.f;
    for (int d = 0; d < 128; ++d) s = fmaf(wq[d * 3 + a], wk[d * 3 + b], s);
    G[ab] = s;
  }
}

// zw[b][c] = b1[c] + sum_{k<512} z[b][k]*w1[c][k]; one wave per output
__global__ __launch_bounds__(256) void zw_k(const float* __restrict__ z,
                                            const float* __restrict__ w1, int ldw,
                                            const float* __restrict__ b1,
                                            float* __restrict__ zw) {
  int wid = blockIdx.x * 4 + (threadIdx.x >> 6);   // 0..4095
  int lane = threadIdx.x & 63;
  int b = wid >> 9, c = wid & 511;
  const float* zr = z + b * 512;
  const float* wr = w1 + (size_t)c * ldw;
  float acc = 0.f;
#pragma unroll
  for (int k = lane; k < 512; k += 64) acc = fmaf(zr[k], wr[k], acc);
#pragma unroll
  for (int off = 32; off; off >>= 1) acc += __shfl_down(acc, off);
  if (lane == 0) zw[wid] = acc + b1[c];
}

// fused per-stage weight prep: ubuf (3x512), w1abf (512x128, s>0), w2bf (512x512)
__global__ __launch_bounds__(256) void prep_k(const float* __restrict__ w1, int ldw,
                                              const float* __restrict__ w2,
                                              float* __restrict__ ubuf,
                                              u16* __restrict__ w1abf,
                                              u16* __restrict__ w2bf, int doW1a) {
  int idx = blockIdx.x * 256 + threadIdx.x;        // 1024 blocks = 262144
  if (idx < 1536) {
    int a = idx >> 9, c = idx & 511;
    ubuf[idx] = w1[(size_t)c * ldw + 512 + a];
  }
  if (doW1a && idx < 65536) {
    int n = idx >> 7, k = idx & 127;
    w1abf[idx] = f2u(w1[(size_t)n * 643 + 515 + k]);
  }
  w2bf[idx] = f2u(w2[idx]);
}

// stage0 layer1: h[i][c] = zw[b][c] + t.x*u0[c] + t.y*u1[c] + t.z*u2[c]
__global__ __launch_bounds__(256) void s0l1_k(const float* __restrict__ tmpl,
                                              const float* __restrict__ u,
                                              const float* __restrict__ zw,
                                              u16* __restrict__ h) {
  int i = blockIdx.x;
  int b = i >> 12, n = i & (NPTS - 1);
  float tx = tmpl[n * 3], ty = tmpl[n * 3 + 1], tz = tmpl[n * 3 + 2];
  const float* zr = zw + b * 512;
#pragma unroll
  for (int c = threadIdx.x; c < 512; c += 256) {
    float v = zr[c] + tx * u[c] + ty * u[512 + c] + tz * u[1024 + c];
    h[(size_t)i * 512 + c] = f2u(v);
  }
}

// ---------------------------------------------------------------------------
// MFMA GEMM: C[m][n] = sum_k A[m][k]*B[n][k] + epilogue. A:MxK bf16, B:NxK bf16.
// 128x128 tile, BK=32, 4 waves x (4x4) 16x16x32 MFMAs. N=512, ldc=512.
// Staging via global_load_lds width=16 into UNPADDED 64B-stride LDS rows.
template <bool MODE1>
__global__ __launch_bounds__(256) void gemm_mfma_k(
    const u16* __restrict__ A, int lda, const u16* __restrict__ B, int ldb, int K,
    const float* __restrict__ bias, const float* __restrict__ zw,
    const float* __restrict__ u, const float4* __restrict__ c4,
    u16* __restrict__ C) {
  __shared__ u16 As[128 * 32];   // 8 KB, row r at As+r*32
  __shared__ u16 Bs[128 * 32];   // 8 KB
  int tid = threadIdx.x;
  int wave = tid >> 6, lane = tid & 63;
  int quad = lane >> 4, l16 = lane & 15;
  int m0 = blockIdx.x * 128, n0 = blockIdx.y * 128;
  int wm = (wave & 1) * 64, wn = (wave >> 1) * 64;
  int srow0 = lane >> 2;          // 0..15 within chunk
  int sc8 = (lane & 3) * 8;       // k-subcol *8
  f4v acc[4][4];
#pragma unroll
  for (int mi = 0; mi < 4; ++mi)
#pragma unroll
    for (int ni = 0; ni < 4; ++ni) acc[mi][ni] = (f4v){0.f, 0.f, 0.f, 0.f};

  for (int k0 = 0; k0 < K; k0 += 32) {
#pragma unroll
    for (int j = 0; j < 2; ++j) {
      int chunk = wave * 2 + j;
      int row = chunk * 16 + srow0;
      const u16* gA = A + (size_t)(m0 + row) * lda + k0 + sc8;
      const u16* gB = B + (size_t)(n0 + row) * ldb + k0 + sc8;
      __builtin_amdgcn_global_load_lds(
          (const __attribute__((address_space(1))) void*)gA,
          (__attribute__((address_space(3))) void*)(As + chunk * 512), 16, 0, 0);
      __builtin_amdgcn_global_load_lds(
          (const __attribute__((address_space(1))) void*)gB,
          (__attribute__((address_space(3))) void*)(Bs + chunk * 512), 16, 0, 0);
    }
    __syncthreads();
    s8v af[4], bfv[4];
#pragma unroll
    for (int mi = 0; mi < 4; ++mi)
      af[mi] = *(const s8v*)&As[(wm + mi * 16 + l16) * 32 + quad * 8];
#pragma unroll
    for (int ni = 0; ni < 4; ++ni)
      bfv[ni] = *(const s8v*)&Bs[(wn + ni * 16 + l16) * 32 + quad * 8];
#pragma unroll
    for (int mi = 0; mi < 4; ++mi)
#pragma unroll
      for (int ni = 0; ni < 4; ++ni)
        acc[mi][ni] = __builtin_amdgcn_mfma_f32_16x16x32_bf16(
            af[mi], bfv[ni], acc[mi][ni], 0, 0, 0);
    __syncthreads();
  }

  // epilogue
  int batch = m0 >> 12;
  float e0[4], e1[4], e2[4], e3[4];
#pragma unroll
  for (int ni = 0; ni < 4; ++ni) {
    int gn = n0 + wn + ni * 16 + l16;
    if (MODE1) {
      e0[ni] = zw[batch * 512 + gn];
      e1[ni] = u[gn];
      e2[ni] = u[512 + gn];
      e3[ni] = u[1024 + gn];
    } else {
      e0[ni] = bias[gn];
    }
  }
#pragma unroll
  for (int mi = 0; mi < 4; ++mi) {
#pragma unroll
    for (int reg = 0; reg < 4; ++reg) {
      int gm = m0 + wm + mi * 16 + quad * 4 + reg;
      float cx = 0.f, cy = 0.f, cz = 0.f;
      if (MODE1) {
        float4 p = c4[gm];
        cx = p.x; cy = p.y; cz = p.z;
      }
#pragma unroll
      for (int ni = 0; ni < 4; ++ni) {
        int gn = n0 + wn + ni * 16 + l16;
        float v = acc[mi][ni][reg] + e0[ni];
        if (MODE1) v += cx * e1[ni] + cy * e2[ni] + cz * e3[ni];
        C[(size_t)gm * 512 + gn] = f2u(v);
      }
    }
  }
}

// ---------------------------------------------------------------------------
// BN stats: 2048 slabs x 16 rows (8 blocks/CU for latency hiding)
__global__ __launch_bounds__(256) void bn_stats_k(const u16* __restrict__ h,
                                                  float* __restrict__ psum,
                                                  float* __restrict__ psumsq) {
  int g = blockIdx.x;                 // 2048
  int c2 = threadIdx.x * 2;
  const u16* base = h + (size_t)g * 16 * 512;
  float s0 = 0, q0 = 0, s1 = 0, q1 = 0;
#pragma unroll
  for (int r = 0; r < 16; ++r) {
    u32 uu = *(const u32*)(base + (size_t)r * 512 + c2);
    float v0 = u2f((u16)(uu & 0xffffu));
    float v1 = u2f((u16)(uu >> 16));
    s0 += v0; q0 += v0 * v0;
    s1 += v1; q1 += v1 * v1;
  }
  psum[g * 512 + c2] = s0; psum[g * 512 + c2 + 1] = s1;
  psumsq[g * 512 + c2] = q0; psumsq[g * 512 + c2 + 1] = q1;
}

__global__ void bn_fin_k(const float* __restrict__ psum, const float* __restrict__ psumsq,
                         const float* __restrict__ gamma, const float* __restrict__ beta,
                         float* __restrict__ sc, float* __restrict__ sh) {
  int c = blockIdx.x * 256 + threadIdx.x;   // 512
  float s = 0, q = 0;
  for (int g = 0; g < 2048; ++g) { s += psum[g * 512 + c]; q += psumsq[g * 512 + c]; }
  float mean = s * (1.f / 32768.f);
  float var = fmaxf(q * (1.f / 32768.f) - mean * mean, 0.f);
  float inv = rsqrtf(var + 1e-5f);
  float scale = gamma[c] * inv;
  sc[c] = scale;
  sh[c] = beta[c] - mean * scale;
}

// a = relu(h*sc+sh), bf16->bf16, 8 elems/thread
__global__ __launch_bounds__(256) void apply_k(const u16* __restrict__ h,
                                               const float* __restrict__ sc,
                                               const float* __restrict__ sh,
                                               u16* __restrict__ a) {
  size_t base = ((size_t)blockIdx.x * 256 + threadIdx.x) * 8;
  int c0 = (int)(base & 511);
  uint4 hv = *(const uint4*)(h + base);
  u16 ov[8];
  const u16* hp = (const u16*)&hv;
#pragma unroll
  for (int j = 0; j < 8; ++j) {
    float x = fmaxf(fmaf(u2f(hp[j]), sc[c0 + j], sh[c0 + j]), 0.f);
    ov[j] = f2u(x);
  }
  *(uint4*)(a + base) = *(const uint4*)ov;
}

// ---------------------------------------------------------------------------
// layer3 (BN fused): coords = relu(h*sc+sh) @ w3^T + b3; wave per row
__global__ __launch_bounds__(256) void l3_k(const u16* __restrict__ h,
                                            const float* __restrict__ sc,
                                            const float* __restrict__ sh,
                                            const float* __restrict__ w3,
                                            const float* __restrict__ b3,
                                            float4* __restrict__ c4out,
                                            float* __restrict__ fout) {
  int wid = blockIdx.x * 4 + (threadIdx.x >> 6);
  int lane = threadIdx.x & 63;
  int k0 = lane * 8;
  uint4 hv = *(const uint4*)(h + (size_t)wid * 512 + k0);
  const u16* hp = (const u16*)&hv;
  float a0 = 0, a1 = 0, a2 = 0;
#pragma unroll
  for (int j = 0; j < 8; ++j) {
    int k = k0 + j;
    float x = fmaxf(fmaf(u2f(hp[j]), sc[k], sh[k]), 0.f);
    a0 = fmaf(x, w3[k], a0);
    a1 = fmaf(x, w3[512 + k], a1);
    a2 = fmaf(x, w3[1024 + k], a2);
  }
#pragma unroll
  for (int off = 32; off; off >>= 1) {
    a0 += __shfl_down(a0, off);
    a1 += __shfl_down(a1, off);
    a2 += __shfl_down(a2, off);
  }
  if (lane == 0) {
    a0 += b3[0]; a1 += b3[1]; a2 += b3[2];
    if (c4out) {
      float sq = a0 * a0 + a1 * a1 + a2 * a2;
      c4out[wid] = make_float4(a0, a1, a2, sq);
    }
    if (fout) {
      fout[(size_t)wid * 3 + 0] = a0;
      fout[(size_t)wid * 3 + 1] = a1;
      fout[(size_t)wid * 3 + 2] = a2;
    }
  }
}

// ---------------------------------------------------------------------------
// Attention: rank-3 identity + per-lane online softmax; wave-uniform ballot
// guard skips the softmax body for the ~70% of chunks with zero hits.
__global__ __launch_bounds__(256) void attn_k(const float4* __restrict__ c4,
                                              const float* __restrict__ G,
                                              const float* __restrict__ wv,
                                              u16* __restrict__ attnb) {
  int wave = threadIdx.x >> 6, lane = threadIdx.x & 63;
  int i = blockIdx.x * 4 + wave;
  int b = i >> 12;
  const float4* cb = c4 + (size_t)b * NPTS;
  float4 cq = c4[i];
  float cx = cq.x, cy = cq.y, cz = cq.z, sqn = cq.w;
  float qg0 = (cx * G[0] + cy * G[3] + cz * G[6]) * INV_SQRT_D;
  float qg1 = (cx * G[1] + cy * G[4] + cz * G[7]) * INV_SQRT_D;
  float qg2 = (cx * G[2] + cy * G[5] + cz * G[8]) * INV_SQRT_D;

  float mloc = -1e30f, swv = 0.f, sxv = 0.f, syv = 0.f, szv = 0.f;
  for (int m0 = 0; m0 < NPTS; m0 += 64) {
    float4 p = cb[m0 + lane];
    float d2 = sqn + p.w - 2.f * (cx * p.x + cy * p.y + cz * p.z);
    bool msk = (d2 <= R_ATT2);
    if (__ballot(msk)) {            // wave-uniform skip of empty chunks
      if (msk) {
        float s = qg0 * p.x + qg1 * p.y + qg2 * p.z;
        float nm = fmaxf(mloc, s);
        float corr = __expf(mloc - nm);
        float wgt = __expf(s - nm);
        swv = swv * corr + wgt;
        sxv = sxv * corr + wgt * p.x;
        syv = syv * corr + wgt * p.y;
        szv = szv * corr + wgt * p.z;
        mloc = nm;
      }
    }
  }
  // online merge across 64 lanes
#pragma unroll
  for (int off = 32; off; off >>= 1) {
    float m2 = __shfl_down(mloc, off);
    float sw2 = __shfl_down(swv, off);
    float sx2 = __shfl_down(sxv, off);
    float sy2 = __shfl_down(syv, off);
    float sz2 = __shfl_down(szv, off);
    float nm = fmaxf(mloc, m2);
    float c1 = __expf(mloc - nm), c2 = __expf(m2 - nm);
    swv = swv * c1 + sw2 * c2;
    sxv = sxv * c1 + sx2 * c2;
    syv = syv * c1 + sy2 * c2;
    szv = szv * c1 + sz2 * c2;
    mloc = nm;
  }
  swv = __shfl(swv, 0); sxv = __shfl(sxv, 0);
  syv = __shfl(syv, 0); szv = __shfl(szv, 0);
  float inv = 1.f / swv;
  float ox = sxv * inv, oy = syv * inv, oz = szv * inv;

  int d0 = lane * 2;
  float v0 = ox * wv[d0 * 3] + oy * wv[d0 * 3 + 1] + oz * wv[d0 * 3 + 2];
  float v1 = ox * wv[d0 * 3 + 3] + oy * wv[d0 * 3 + 4] + oz * wv[d0 * 3 + 5];
  u32 pack = (u32)f2u(v0) | ((u32)f2u(v1) << 16);
  *(u32*)(attnb + (size_t)i * 128 + d0) = pack;
}

// ---------------------------------------------------------------------------
extern "C" void kernel_launch(void* const* d_in, const int* in_sizes, int n_in,
                              void* d_out, int out_size, void* d_ws, size_t ws_size,
                              hipStream_t stream) {
  const float* z = (const float*)d_in[0];
  const float* tmpl = (const float*)d_in[1];
  const float* wq = (const float*)d_in[2];
  const float* wk = (const float*)d_in[3];
  const float* wv = (const float*)d_in[4];
  const float* sw[3][10];
  for (int s = 0; s < 3; ++s)
    for (int j = 0; j < 10; ++j) sw[s][j] = (const float*)d_in[5 + s * 10 + j];
  // j: 0=w1 1=b1 2=g1 3=be1 4=w2 5=b2 6=g2 7=be2 8=w3 9=b3

  char* base = (char*)d_ws;
  size_t off = 0;
  auto alloc = [&](size_t bytes) -> void* {
    void* p = base + off;
    off = (off + bytes + 255) & ~(size_t)255;
    return p;
  };
  u16* hA = (u16*)alloc((size_t)ROWS * 512 * 2);        // 33.55 MB
  u16* hB = (u16*)alloc((size_t)ROWS * 512 * 2);        // 33.55 MB
  u16* attnb = (u16*)alloc((size_t)ROWS * 128 * 2);     //  8.39 MB
  float4* c4 = (float4*)alloc((size_t)ROWS * 16);       //  0.52 MB
  float* zwbuf = (float*)alloc(4096 * 4);
  float* scv = (float*)alloc(512 * 4);
  float* shv = (float*)alloc(512 * 4);
  float* G = (float*)alloc(256);
  u16* w1abf = (u16*)alloc(512 * 128 * 2);
  u16* w2bf = (u16*)alloc(512 * 512 * 2);
  float* ubuf = (float*)alloc(1536 * 4);
  // psum/psumsq (2048x512 each = 8 MB total) alias attnb (8.389 MB),
  // dead between GEMM1-read and attn-write
  float* psum = (float*)attnb;
  float* psumsq = psum + 2048 * 512;

  gram_k<<<1, 64, 0, stream>>>(wq, wk, G);

  for (int s = 0; s < 3; ++s) {
    int ldw = (s == 0) ? 515 : 643;
    zw_k<<<1024, 256, 0, stream>>>(z, sw[s][0], ldw, sw[s][1], zwbuf);
    prep_k<<<1024, 256, 0, stream>>>(sw[s][0], ldw, sw[s][4], ubuf, w1abf, w2bf,
                                     s == 0 ? 0 : 1);
    if (s == 0) {
      s0l1_k<<<ROWS, 256, 0, stream>>>(tmpl, ubuf, zwbuf, hA);
    } else {
      gemm_mfma_k<true><<<dim3(256, 4), 256, 0, stream>>>(
          attnb, 128, w1abf, 128, 128, nullptr, zwbuf, ubuf, c4, hA);
    }
    bn_stats_k<<<2048, 256, 0, stream>>>(hA, psum, psumsq);
    bn_fin_k<<<2, 256, 0, stream>>>(psum, psumsq, sw[s][2], sw[s][3], scv, shv);
    apply_k<<<8192, 256, 0, stream>>>(hA, scv, shv, hB);
    gemm_mfma_k<false><<<dim3(256, 4), 256, 0, stream>>>(
        hB, 512, w2bf, 512, 512, sw[s][5], nullptr, nullptr, nullptr, hA);
    bn_stats_k<<<2048, 256, 0, stream>>>(hA, psum, psumsq);
    bn_fin_k<<<2, 256, 0, stream>>>(psum, psumsq, sw[s][6], sw[s][7], scv, shv);
    bool last = (s == 2);
    l3_k<<<8192, 256, 0, stream>>>(hA, scv, shv, sw[s][8], sw[s][9],
                                   last ? nullptr : c4,
                                   last ? (float*)d_out : nullptr);
    if (!last) {
      attn_k<<<8192, 256, 0, stream>>>(c4, G, wv, attnb);
    }
  }
}

// Round 11
// 713.633 us; speedup vs baseline: 1.7785x; 1.7785x over previous
//
#include <hip/hip_runtime.h>
#include <math.h>

#define NPTS 4096
#define BATCH 8
#define HIDD 512
#define ROWS 32768
#define R_ATT2 0.04f
#define INV_SQRT_D 0.08838834764831845f

typedef unsigned short u16;
typedef unsigned int u32;
typedef __attribute__((ext_vector_type(8))) short s8v;
typedef __attribute__((ext_vector_type(4))) float f4v;

__device__ __forceinline__ float u2f(u16 v) { return __uint_as_float(((u32)v) << 16); }
__device__ __forceinline__ u16 f2u(float f) {         // RNE fp32->bf16
  u32 u = __float_as_uint(f);
  return (u16)((u + 0x7fffu + ((u >> 16) & 1u)) >> 16);
}

// ---------------------------------------------------------------------------
// G = wq^T @ wk (3x3)
__global__ void gram_k(const float* __restrict__ wq, const float* __restrict__ wk,
                       float* __restrict__ G) {
  int ab = threadIdx.x;
  if (ab < 9) {
    int a = ab / 3, b = ab % 3;
    float s = 0.f;
    for (int d = 0; d < 128; ++d) s = fmaf(wq[d * 3 + a], wk[d * 3 + b], s);
    G[ab] = s;
  }
}

// zw[b][c] = b1[c] + sum_{k<512} z[b][k]*w1[c][k]; one wave per output
__global__ __launch_bounds__(256) void zw_k(const float* __restrict__ z,
                                            const float* __restrict__ w1, int ldw,
                                            const float* __restrict__ b1,
                                            float* __restrict__ zw) {
  int wid = blockIdx.x * 4 + (threadIdx.x >> 6);   // 0..4095
  int lane = threadIdx.x & 63;
  int b = wid >> 9, c = wid & 511;
  const float* zr = z + b * 512;
  const float* wr = w1 + (size_t)c * ldw;
  float acc = 0.f;
#pragma unroll
  for (int k = lane; k < 512; k += 64) acc = fmaf(zr[k], wr[k], acc);
#pragma unroll
  for (int off = 32; off; off >>= 1) acc += __shfl_down(acc, off);
  if (lane == 0) zw[wid] = acc + b1[c];
}

// fused per-stage weight prep: ubuf (3x512), w1abf (512x128, s>0), w2bf (512x512)
__global__ __launch_bounds__(256) void prep_k(const float* __restrict__ w1, int ldw,
                                              const float* __restrict__ w2,
                                              float* __restrict__ ubuf,
                                              u16* __restrict__ w1abf,
                                              u16* __restrict__ w2bf, int doW1a) {
  int idx = blockIdx.x * 256 + threadIdx.x;        // 1024 blocks = 262144
  if (idx < 1536) {
    int a = idx >> 9, c = idx & 511;
    ubuf[idx] = w1[(size_t)c * ldw + 512 + a];
  }
  if (doW1a && idx < 65536) {
    int n = idx >> 7, k = idx & 127;
    w1abf[idx] = f2u(w1[(size_t)n * 643 + 515 + k]);
  }
  w2bf[idx] = f2u(w2[idx]);
}

// stage0 layer1: h[i][c] = zw[b][c] + t.x*u0[c] + t.y*u1[c] + t.z*u2[c]
__global__ __launch_bounds__(256) void s0l1_k(const float* __restrict__ tmpl,
                                              const float* __restrict__ u,
                                              const float* __restrict__ zw,
                                              u16* __restrict__ h) {
  int i = blockIdx.x;
  int b = i >> 12, n = i & (NPTS - 1);
  float tx = tmpl[n * 3], ty = tmpl[n * 3 + 1], tz = tmpl[n * 3 + 2];
  const float* zr = zw + b * 512;
#pragma unroll
  for (int c = threadIdx.x; c < 512; c += 256) {
    float v = zr[c] + tx * u[c] + ty * u[512 + c] + tz * u[1024 + c];
    h[(size_t)i * 512 + c] = f2u(v);
  }
}

// ---------------------------------------------------------------------------
// MFMA GEMM: C[m][n] = sum_k A[m][k]*B[n][k] + epilogue. A:MxK bf16, B:NxK bf16.
// 128x128 tile, BK=32, 4 waves x (4x4) 16x16x32 MFMAs. N=512, ldc=512.
// Staging via global_load_lds width=16 into UNPADDED 64B-stride LDS rows.
template <bool MODE1>
__global__ __launch_bounds__(256) void gemm_mfma_k(
    const u16* __restrict__ A, int lda, const u16* __restrict__ B, int ldb, int K,
    const float* __restrict__ bias, const float* __restrict__ zw,
    const float* __restrict__ u, const float4* __restrict__ c4,
    u16* __restrict__ C) {
  __shared__ u16 As[128 * 32];   // 8 KB, row r at As+r*32
  __shared__ u16 Bs[128 * 32];   // 8 KB
  int tid = threadIdx.x;
  int wave = tid >> 6, lane = tid & 63;
  int quad = lane >> 4, l16 = lane & 15;
  int m0 = blockIdx.x * 128, n0 = blockIdx.y * 128;
  int wm = (wave & 1) * 64, wn = (wave >> 1) * 64;
  int srow0 = lane >> 2;          // 0..15 within chunk
  int sc8 = (lane & 3) * 8;       // k-subcol *8
  f4v acc[4][4];
#pragma unroll
  for (int mi = 0; mi < 4; ++mi)
#pragma unroll
    for (int ni = 0; ni < 4; ++ni) acc[mi][ni] = (f4v){0.f, 0.f, 0.f, 0.f};

  for (int k0 = 0; k0 < K; k0 += 32) {
#pragma unroll
    for (int j = 0; j < 2; ++j) {
      int chunk = wave * 2 + j;
      int row = chunk * 16 + srow0;
      const u16* gA = A + (size_t)(m0 + row) * lda + k0 + sc8;
      const u16* gB = B + (size_t)(n0 + row) * ldb + k0 + sc8;
      __builtin_amdgcn_global_load_lds(
          (const __attribute__((address_space(1))) void*)gA,
          (__attribute__((address_space(3))) void*)(As + chunk * 512), 16, 0, 0);
      __builtin_amdgcn_global_load_lds(
          (const __attribute__((address_space(1))) void*)gB,
          (__attribute__((address_space(3))) void*)(Bs + chunk * 512), 16, 0, 0);
    }
    __syncthreads();
    s8v af[4], bfv[4];
#pragma unroll
    for (int mi = 0; mi < 4; ++mi)
      af[mi] = *(const s8v*)&As[(wm + mi * 16 + l16) * 32 + quad * 8];
#pragma unroll
    for (int ni = 0; ni < 4; ++ni)
      bfv[ni] = *(const s8v*)&Bs[(wn + ni * 16 + l16) * 32 + quad * 8];
#pragma unroll
    for (int mi = 0; mi < 4; ++mi)
#pragma unroll
      for (int ni = 0; ni < 4; ++ni)
        acc[mi][ni] = __builtin_amdgcn_mfma_f32_16x16x32_bf16(
            af[mi], bfv[ni], acc[mi][ni], 0, 0, 0);
    __syncthreads();
  }

  // epilogue
  int batch = m0 >> 12;
  float e0[4], e1[4], e2[4], e3[4];
#pragma unroll
  for (int ni = 0; ni < 4; ++ni) {
    int gn = n0 + wn + ni * 16 + l16;
    if (MODE1) {
      e0[ni] = zw[batch * 512 + gn];
      e1[ni] = u[gn];
      e2[ni] = u[512 + gn];
      e3[ni] = u[1024 + gn];
    } else {
      e0[ni] = bias[gn];
    }
  }
#pragma unroll
  for (int mi = 0; mi < 4; ++mi) {
#pragma unroll
    for (int reg = 0; reg < 4; ++reg) {
      int gm = m0 + wm + mi * 16 + quad * 4 + reg;
      float cx = 0.f, cy = 0.f, cz = 0.f;
      if (MODE1) {
        float4 p = c4[gm];
        cx = p.x; cy = p.y; cz = p.z;
      }
#pragma unroll
      for (int ni = 0; ni < 4; ++ni) {
        int gn = n0 + wn + ni * 16 + l16;
        float v = acc[mi][ni][reg] + e0[ni];
        if (MODE1) v += cx * e1[ni] + cy * e2[ni] + cz * e3[ni];
        C[(size_t)gm * 512 + gn] = f2u(v);
      }
    }
  }
}

// ---------------------------------------------------------------------------
// BN stats: 2048 slabs x 16 rows (8 blocks/CU for latency hiding)
__global__ __launch_bounds__(256) void bn_stats_k(const u16* __restrict__ h,
                                                  float* __restrict__ psum,
                                                  float* __restrict__ psumsq) {
  int g = blockIdx.x;                 // 2048
  int c2 = threadIdx.x * 2;
  const u16* base = h + (size_t)g * 16 * 512;
  float s0 = 0, q0 = 0, s1 = 0, q1 = 0;
#pragma unroll
  for (int r = 0; r < 16; ++r) {
    u32 uu = *(const u32*)(base + (size_t)r * 512 + c2);
    float v0 = u2f((u16)(uu & 0xffffu));
    float v1 = u2f((u16)(uu >> 16));
    s0 += v0; q0 += v0 * v0;
    s1 += v1; q1 += v1 * v1;
  }
  psum[g * 512 + c2] = s0; psum[g * 512 + c2 + 1] = s1;
  psumsq[g * 512 + c2] = q0; psumsq[g * 512 + c2 + 1] = q1;
}

// BN finalize: wave-per-channel (512 waves = 128 blocks x 4) — the round-10
// version ran 8 waves total and serialized ~4096 L2 loads per thread (+80 µs).
__global__ __launch_bounds__(256) void bn_fin_k(
    const float* __restrict__ psum, const float* __restrict__ psumsq,
    const float* __restrict__ gamma, const float* __restrict__ beta,
    float* __restrict__ sc, float* __restrict__ sh) {
  int c = blockIdx.x * 4 + (threadIdx.x >> 6);   // 0..511
  int lane = threadIdx.x & 63;
  float s = 0.f, q = 0.f;
  for (int g = lane; g < 2048; g += 64) {
    s += psum[g * 512 + c];
    q += psumsq[g * 512 + c];
  }
#pragma unroll
  for (int off = 32; off; off >>= 1) {
    s += __shfl_down(s, off);
    q += __shfl_down(q, off);
  }
  if (lane == 0) {
    float mean = s * (1.f / 32768.f);
    float var = fmaxf(q * (1.f / 32768.f) - mean * mean, 0.f);
    float inv = rsqrtf(var + 1e-5f);
    float scale = gamma[c] * inv;
    sc[c] = scale;
    sh[c] = beta[c] - mean * scale;
  }
}

// a = relu(h*sc+sh), bf16->bf16, 8 elems/thread
__global__ __launch_bounds__(256) void apply_k(const u16* __restrict__ h,
                                               const float* __restrict__ sc,
                                               const float* __restrict__ sh,
                                               u16* __restrict__ a) {
  size_t base = ((size_t)blockIdx.x * 256 + threadIdx.x) * 8;
  int c0 = (int)(base & 511);
  uint4 hv = *(const uint4*)(h + base);
  u16 ov[8];
  const u16* hp = (const u16*)&hv;
#pragma unroll
  for (int j = 0; j < 8; ++j) {
    float x = fmaxf(fmaf(u2f(hp[j]), sc[c0 + j], sh[c0 + j]), 0.f);
    ov[j] = f2u(x);
  }
  *(uint4*)(a + base) = *(const uint4*)ov;
}

// ---------------------------------------------------------------------------
// layer3 (BN fused): coords = relu(h*sc+sh) @ w3^T + b3; wave per row
__global__ __launch_bounds__(256) void l3_k(const u16* __restrict__ h,
                                            const float* __restrict__ sc,
                                            const float* __restrict__ sh,
                                            const float* __restrict__ w3,
                                            const float* __restrict__ b3,
                                            float4* __restrict__ c4out,
                                            float* __restrict__ fout) {
  int wid = blockIdx.x * 4 + (threadIdx.x >> 6);
  int lane = threadIdx.x & 63;
  int k0 = lane * 8;
  uint4 hv = *(const uint4*)(h + (size_t)wid * 512 + k0);
  const u16* hp = (const u16*)&hv;
  float a0 = 0, a1 = 0, a2 = 0;
#pragma unroll
  for (int j = 0; j < 8; ++j) {
    int k = k0 + j;
    float x = fmaxf(fmaf(u2f(hp[j]), sc[k], sh[k]), 0.f);
    a0 = fmaf(x, w3[k], a0);
    a1 = fmaf(x, w3[512 + k], a1);
    a2 = fmaf(x, w3[1024 + k], a2);
  }
#pragma unroll
  for (int off = 32; off; off >>= 1) {
    a0 += __shfl_down(a0, off);
    a1 += __shfl_down(a1, off);
    a2 += __shfl_down(a2, off);
  }
  if (lane == 0) {
    a0 += b3[0]; a1 += b3[1]; a2 += b3[2];
    if (c4out) {
      float sq = a0 * a0 + a1 * a1 + a2 * a2;
      c4out[wid] = make_float4(a0, a1, a2, sq);
    }
    if (fout) {
      fout[(size_t)wid * 3 + 0] = a0;
      fout[(size_t)wid * 3 + 1] = a1;
      fout[(size_t)wid * 3 + 2] = a2;
    }
  }
}

// ---------------------------------------------------------------------------
// Attention: rank-3 identity + per-lane online softmax (round-7 v1 form).
__global__ __launch_bounds__(256) void attn_k(const float4* __restrict__ c4,
                                              const float* __restrict__ G,
                                              const float* __restrict__ wv,
                                              u16* __restrict__ attnb) {
  int wave = threadIdx.x >> 6, lane = threadIdx.x & 63;
  int i = blockIdx.x * 4 + wave;
  int b = i >> 12;
  const float4* cb = c4 + (size_t)b * NPTS;
  float4 cq = c4[i];
  float cx = cq.x, cy = cq.y, cz = cq.z, sqn = cq.w;
  float qg0 = (cx * G[0] + cy * G[3] + cz * G[6]) * INV_SQRT_D;
  float qg1 = (cx * G[1] + cy * G[4] + cz * G[7]) * INV_SQRT_D;
  float qg2 = (cx * G[2] + cy * G[5] + cz * G[8]) * INV_SQRT_D;

  float mloc = -1e30f, swv = 0.f, sxv = 0.f, syv = 0.f, szv = 0.f;
  for (int m0 = 0; m0 < NPTS; m0 += 64) {
    float4 p = cb[m0 + lane];
    float d2 = sqn + p.w - 2.f * (cx * p.x + cy * p.y + cz * p.z);
    if (d2 <= R_ATT2) {
      float s = qg0 * p.x + qg1 * p.y + qg2 * p.z;
      float nm = fmaxf(mloc, s);
      float corr = __expf(mloc - nm);
      float wgt = __expf(s - nm);
      swv = swv * corr + wgt;
      sxv = sxv * corr + wgt * p.x;
      syv = syv * corr + wgt * p.y;
      szv = szv * corr + wgt * p.z;
      mloc = nm;
    }
  }
  // online merge across 64 lanes
#pragma unroll
  for (int off = 32; off; off >>= 1) {
    float m2 = __shfl_down(mloc, off);
    float sw2 = __shfl_down(swv, off);
    float sx2 = __shfl_down(sxv, off);
    float sy2 = __shfl_down(syv, off);
    float sz2 = __shfl_down(szv, off);
    float nm = fmaxf(mloc, m2);
    float c1 = __expf(mloc - nm), c2 = __expf(m2 - nm);
    swv = swv * c1 + sw2 * c2;
    sxv = sxv * c1 + sx2 * c2;
    syv = syv * c1 + sy2 * c2;
    szv = szv * c1 + sz2 * c2;
    mloc = nm;
  }
  swv = __shfl(swv, 0); sxv = __shfl(sxv, 0);
  syv = __shfl(syv, 0); szv = __shfl(szv, 0);
  float inv = 1.f / swv;
  float ox = sxv * inv, oy = syv * inv, oz = szv * inv;

  int d0 = lane * 2;
  float v0 = ox * wv[d0 * 3] + oy * wv[d0 * 3 + 1] + oz * wv[d0 * 3 + 2];
  float v1 = ox * wv[d0 * 3 + 3] + oy * wv[d0 * 3 + 4] + oz * wv[d0 * 3 + 5];
  u32 pack = (u32)f2u(v0) | ((u32)f2u(v1) << 16);
  *(u32*)(attnb + (size_t)i * 128 + d0) = pack;
}

// ---------------------------------------------------------------------------
extern "C" void kernel_launch(void* const* d_in, const int* in_sizes, int n_in,
                              void* d_out, int out_size, void* d_ws, size_t ws_size,
                              hipStream_t stream) {
  const float* z = (const float*)d_in[0];
  const float* tmpl = (const float*)d_in[1];
  const float* wq = (const float*)d_in[2];
  const float* wk = (const float*)d_in[3];
  const float* wv = (const float*)d_in[4];
  const float* sw[3][10];
  for (int s = 0; s < 3; ++s)
    for (int j = 0; j < 10; ++j) sw[s][j] = (const float*)d_in[5 + s * 10 + j];
  // j: 0=w1 1=b1 2=g1 3=be1 4=w2 5=b2 6=g2 7=be2 8=w3 9=b3

  char* base = (char*)d_ws;
  size_t off = 0;
  auto alloc = [&](size_t bytes) -> void* {
    void* p = base + off;
    off = (off + bytes + 255) & ~(size_t)255;
    return p;
  };
  u16* hA = (u16*)alloc((size_t)ROWS * 512 * 2);        // 33.55 MB
  u16* hB = (u16*)alloc((size_t)ROWS * 512 * 2);        // 33.55 MB
  u16* attnb = (u16*)alloc((size_t)ROWS * 128 * 2);     //  8.39 MB
  float4* c4 = (float4*)alloc((size_t)ROWS * 16);       //  0.52 MB
  float* zwbuf = (float*)alloc(4096 * 4);
  float* scv = (float*)alloc(512 * 4);
  float* shv = (float*)alloc(512 * 4);
  float* G = (float*)alloc(256);
  u16* w1abf = (u16*)alloc(512 * 128 * 2);
  u16* w2bf = (u16*)alloc(512 * 512 * 2);
  float* ubuf = (float*)alloc(1536 * 4);
  // psum/psumsq (2048x512 each = 8 MB total) alias attnb (8.389 MB),
  // dead between GEMM1-read and attn-write
  float* psum = (float*)attnb;
  float* psumsq = psum + 2048 * 512;

  gram_k<<<1, 64, 0, stream>>>(wq, wk, G);

  for (int s = 0; s < 3; ++s) {
    int ldw = (s == 0) ? 515 : 643;
    zw_k<<<1024, 256, 0, stream>>>(z, sw[s][0], ldw, sw[s][1], zwbuf);
    prep_k<<<1024, 256, 0, stream>>>(sw[s][0], ldw, sw[s][4], ubuf, w1abf, w2bf,
                                     s == 0 ? 0 : 1);
    if (s == 0) {
      s0l1_k<<<ROWS, 256, 0, stream>>>(tmpl, ubuf, zwbuf, hA);
    } else {
      gemm_mfma_k<true><<<dim3(256, 4), 256, 0, stream>>>(
          attnb, 128, w1abf, 128, 128, nullptr, zwbuf, ubuf, c4, hA);
    }
    bn_stats_k<<<2048, 256, 0, stream>>>(hA, psum, psumsq);
    bn_fin_k<<<128, 256, 0, stream>>>(psum, psumsq, sw[s][2], sw[s][3], scv, shv);
    apply_k<<<8192, 256, 0, stream>>>(hA, scv, shv, hB);
    gemm_mfma_k<false><<<dim3(256, 4), 256, 0, stream>>>(
        hB, 512, w2bf, 512, 512, sw[s][5], nullptr, nullptr, nullptr, hA);
    bn_stats_k<<<2048, 256, 0, stream>>>(hA, psum, psumsq);
    bn_fin_k<<<128, 256, 0, stream>>>(psum, psumsq, sw[s][6], sw[s][7], scv, shv);
    bool last = (s == 2);
    l3_k<<<8192, 256, 0, stream>>>(hA, scv, shv, sw[s][8], sw[s][9],
                                   last ? nullptr : c4,
                                   last ? (float*)d_out : nullptr);
    if (!last) {
      attn_k<<<8192, 256, 0, stream>>>(c4, G, wv, attnb);
    }
  }
}